// Round 1
// baseline (494.570 us; speedup 1.0000x reference)
//
#include <hip/hip_runtime.h>

namespace {

constexpr int MM = 3;
constexpr int BB = 16384;
constexpr int DD = 1024;
constexpr int CC = 100;
constexpr int HH = 2048;             // 2*DD
constexpr int DESIRED = BB / CC;     // 163 (>=1 since B>=C)

// fused copy + proto-partials
constexpr int DR   = 128, DG = DD / DR;   // 8 d-groups
constexpr int BSPL = 16,  CHUNK = BB / BSPL; // 1024 rows per block
// class-GEMM
constexpr int KC  = 16, JL = HH / KC;     // 128 j per block
constexpr int DG2 = 4,  DR2 = 256;        // 4 d-groups of 256

// ws byte offsets
constexpr size_t WS_COUNTS = 0;                               // 128 int
constexpr size_t WS_GEN    = 512;                             // 128 int
constexpr size_t WS_OFF    = 1024;                            // 128 int
constexpr size_t WS_BASE   = 2048;                            // MM*HH f32
constexpr size_t WS_PROTO  = 32768;                           // CC*MM*DD f32
constexpr size_t WS_MASK   = WS_PROTO + (size_t)CC * MM * DD * 4; // CC*MM f32
constexpr size_t WS_ACT    = WS_MASK + 2048;                  // MM*HH*CC f32, layout [m][j][c]
constexpr size_t WS_BIG    = (size_t)4 * 1024 * 1024;         // psum / gpart (aliased)

__global__ void __launch_bounds__(256)
k_zero(float* __restrict__ ws) {
  int i = blockIdx.x * 256 + threadIdx.x;
  if (i < 8192) ws[i] = 0.f;  // zeroes counts/gen/off/base region (32 KB)
}

__global__ void __launch_bounds__(256)
k_count(const int* __restrict__ labels, int* __restrict__ counts,
        float* __restrict__ out_lab) {
  int b = blockIdx.x * 256 + threadIdx.x;
  if (b < BB) {
    int l = labels[b];
    atomicAdd(&counts[l], 1);
    out_lab[b] = (float)l;
  }
}

// one block of 128 threads: gen, exclusive offsets, class-id tail labels, loss
__global__ void __launch_bounds__(128)
k_plan(const int* __restrict__ counts, int* __restrict__ gen, int* __restrict__ off,
       float* __restrict__ out_lab_tail, float* __restrict__ out_loss,
       const float* __restrict__ dw, int N) {
  __shared__ int s[128];
  int t = threadIdx.x;
  int cnt = (t < CC) ? counts[t] : 0;
  int g = (t < CC && cnt > 0) ? max(DESIRED - cnt, 0) : 0;
  s[t] = g;
  __syncthreads();
  for (int o = 1; o < 128; o <<= 1) {
    int v = (t >= o) ? s[t - o] : 0;
    __syncthreads();
    s[t] += v;
    __syncthreads();
  }
  int excl = s[t] - g;
  if (t < CC) {
    gen[t] = g;
    off[t] = excl;
    for (int k = 0; k < g; ++k) out_lab_tail[excl + k] = (float)t;
  }
  if (t == 0) *out_loss = (N > 0) ? 0.1f * dw[0] : 0.0f;
}

// Fused: stream features -> combined[:, :B, :] copy, accumulate per-class
// partial sums in LDS, flush to psum[bs][m][dg][c][d].
__global__ void __launch_bounds__(256)
k_copy_psum(const float* __restrict__ feat, const int* __restrict__ labels,
            float* __restrict__ out, float* __restrict__ psum, int BN) {
  __shared__ float lds[CC * DR];   // 51.2 KB, swizzled: pos(d) = (d%4)*32 + d/4
  __shared__ int slab[CHUNK];      // 4 KB label stage
  int t = threadIdx.x;
  int bs = blockIdx.x, dg = blockIdx.y, m = blockIdx.z;
  int b0 = bs * CHUNK;
  for (int i = t; i < CC * DR; i += 256) lds[i] = 0.f;
  for (int i = t; i < CHUNK; i += 256) slab[i] = labels[b0 + i];
  __syncthreads();

  int r = t >> 5, lane = t & 31;   // 8 rows per iteration
  int d0 = dg * DR + lane * 4;
  for (int b = b0 + r; b < b0 + CHUNK; b += 8) {
    int lab = slab[b - b0];
    const float4 f4 = *reinterpret_cast<const float4*>(
        &feat[((size_t)m * BB + b) * DD + d0]);
    *reinterpret_cast<float4*>(&out[((size_t)m * BN + b) * DD + d0]) = f4;
    atomicAdd(&lds[lab * DR + 0 * 32 + lane], f4.x);
    atomicAdd(&lds[lab * DR + 1 * 32 + lane], f4.y);
    atomicAdd(&lds[lab * DR + 2 * 32 + lane], f4.z);
    atomicAdd(&lds[lab * DR + 3 * 32 + lane], f4.w);
  }
  __syncthreads();
  float* pbase = psum + ((size_t)(bs * MM + m) * DG + dg) * (CC * DR);
  for (int i = t; i < CC * DR; i += 256) {
    int d = i & (DR - 1);
    pbase[i] = lds[(i & ~(DR - 1)) + (d & 3) * 32 + (d >> 2)];
  }
}

// reduce psum over bs, divide by count -> proto[c][m][d]; blend mask
__global__ void __launch_bounds__(256)
k_proto_final(const float* __restrict__ psum, const int* __restrict__ counts,
              float* __restrict__ proto, float* __restrict__ mask) {
  int c = blockIdx.x, m = blockIdx.y, t = threadIdx.x;
  int dg = t >> 5, dr4 = (t & 31) * 4;
  float4 acc = {0.f, 0.f, 0.f, 0.f};
  for (int bs = 0; bs < BSPL; ++bs) {
    const float4 v = *reinterpret_cast<const float4*>(
        &psum[((size_t)(bs * MM + m) * DG + dg) * (CC * DR) + c * DR + dr4]);
    acc.x += v.x; acc.y += v.y; acc.z += v.z; acc.w += v.w;
  }
  int cnt = counts[c];
  float inv = cnt > 0 ? 1.f / (float)cnt : 0.f;
  acc.x *= inv; acc.y *= inv; acc.z *= inv; acc.w *= inv;
  int d0 = dg * DR + dr4;
  *reinterpret_cast<float4*>(&proto[((size_t)c * MM + m) * DD + d0]) = acc;
  float s = acc.x + acc.y + acc.z + acc.w;
  __shared__ float red[256];
  red[t] = s;
  __syncthreads();
  for (int o = 128; o > 0; o >>= 1) {
    if (t < o) red[t] += red[t + o];
    __syncthreads();
  }
  if (t == 0) mask[c * MM + m] = (red[0] > 0.f) ? 1.f : 0.f;
}

// base[m][j] = sum_d fused0[d] * W1[m][d][j]  (atomic partial over d-chunks)
__global__ void __launch_bounds__(256)
k_base(const float* __restrict__ fused, const float* __restrict__ W1,
       float* __restrict__ base) {
  int jb = blockIdx.x, db = blockIdx.y, m = blockIdx.z, t = threadIdx.x;
  int j = jb * 256 + t;
  const float* w = W1 + ((size_t)m * (DD + CC)) * HH + j;
  float acc = 0.f;
  int dlo = db * 128;
  for (int d = dlo; d < dlo + 128; ++d)
    acc = fmaf(fused[d], w[(size_t)d * HH], acc);
  atomicAdd(&base[m * HH + j], acc);
}

// h = base + W1[m][D+c] + b1 -> layernorm -> leaky -> act[m][j][c] (transposed)
__global__ void __launch_bounds__(256)
k_hact(const float* __restrict__ W1, const float* __restrict__ b1,
       const float* __restrict__ lng, const float* __restrict__ lnb,
       const float* __restrict__ base, float* __restrict__ act) {
  int c = blockIdx.x, m = blockIdx.y, t = threadIdx.x;
  const float* w1row = W1 + ((size_t)m * (DD + CC) + DD + c) * HH;
  float h[8];
  float s = 0.f, s2 = 0.f;
#pragma unroll
  for (int k = 0; k < 8; ++k) {
    int j = t + k * 256;
    float v = base[m * HH + j] + w1row[j] + b1[m * HH + j];
    h[k] = v; s += v; s2 += v * v;
  }
  __shared__ float rs[256], rs2[256];
  rs[t] = s; rs2[t] = s2;
  __syncthreads();
  for (int o = 128; o > 0; o >>= 1) {
    if (t < o) { rs[t] += rs[t + o]; rs2[t] += rs2[t + o]; }
    __syncthreads();
  }
  float mu = rs[0] * (1.f / HH);
  float var = rs2[0] * (1.f / HH) - mu * mu;
  float rstd = rsqrtf(var + 1e-5f);
  float* ao = act + (size_t)m * HH * CC;
#pragma unroll
  for (int k = 0; k < 8; ++k) {
    int j = t + k * 256;
    float v = (h[k] - mu) * rstd * lng[m * HH + j] + lnb[m * HH + j];
    v = v > 0.f ? v : 0.2f * v;
    ao[(size_t)j * CC + c] = v;   // transposed for scalar-vectorized gemm reads
  }
}

// gpart[m][dg][kc][c][d'] = sum_{j in chunk} act[m][j][c] * W2[m][j][d]
__global__ void __launch_bounds__(256, 1)
k_gemm(const float* __restrict__ act, const float* __restrict__ W2,
       float* __restrict__ gpart) {
  int dg = blockIdx.x, kc = blockIdx.y, m = blockIdx.z, t = threadIdx.x;
  int d = dg * DR2 + t;
  int j0 = kc * JL;
  float acc[CC];
#pragma unroll
  for (int c = 0; c < CC; ++c) acc[c] = 0.f;
  const float* ab = act + ((size_t)m * HH + j0) * CC;
  const float* wb = W2 + ((size_t)m * HH + j0) * DD + d;
  for (int j = 0; j < JL; ++j) {
    float w2v = wb[(size_t)j * DD];
    const float* aj = ab + (size_t)j * CC;   // uniform across block -> s_loads
#pragma unroll
    for (int c = 0; c < CC; ++c) acc[c] = fmaf(aj[c], w2v, acc[c]);
  }
  float* pb = gpart + ((size_t)(m * DG2 + dg) * KC + kc) * (CC * DR2) + t;
#pragma unroll
  for (int c = 0; c < CC; ++c) pb[c * DR2] = acc[c];
}

// g = sum_kc gpart + b2 -> sequential blend -> scatter to all rows of class c
__global__ void __launch_bounds__(256)
k_final(const float* __restrict__ gpart, const float* __restrict__ proto,
        const float* __restrict__ mask, const float* __restrict__ b2,
        const float* __restrict__ corr, const int* __restrict__ gen,
        const int* __restrict__ off, float* __restrict__ out, int BN) {
  int c = blockIdx.x, m = blockIdx.y, t = threadIdx.x;
  int g = gen[c];
  if (g == 0) return;
  int d0 = t * 4, dg = d0 >> 8, dsub = d0 & 255;
  float4 a = {0.f, 0.f, 0.f, 0.f};
#pragma unroll
  for (int kc = 0; kc < KC; ++kc) {
    const float4 v = *reinterpret_cast<const float4*>(
        &gpart[((size_t)(m * DG2 + dg) * KC + kc) * (CC * DR2) + c * DR2 + dsub]);
    a.x += v.x; a.y += v.y; a.z += v.z; a.w += v.w;
  }
  const float4 bb = *reinterpret_cast<const float4*>(&b2[m * DD + d0]);
  a.x += bb.x; a.y += bb.y; a.z += bb.z; a.w += bb.w;
#pragma unroll
  for (int om = 0; om < MM; ++om) {
    if (om == m) continue;
    float al = corr[m * MM + om] * mask[c * MM + om];
    float ia = 1.f - al;
    const float4 p = *reinterpret_cast<const float4*>(
        &proto[((size_t)c * MM + om) * DD + d0]);
    a.x = a.x * ia + p.x * al;
    a.y = a.y * ia + p.y * al;
    a.z = a.z * ia + p.z * al;
    a.w = a.w * ia + p.w * al;
  }
  int row0 = BB + off[c];
  for (int k = 0; k < g; ++k)
    *reinterpret_cast<float4*>(&out[((size_t)m * BN + row0 + k) * DD + d0]) = a;
}

}  // namespace

extern "C" void kernel_launch(void* const* d_in, const int* in_sizes, int n_in,
                              void* d_out, int out_size, void* d_ws, size_t ws_size,
                              hipStream_t stream) {
  const float* features = (const float*)d_in[0];
  const float* fused    = (const float*)d_in[1];
  const int*   labels   = (const int*)d_in[2];
  const float* W1       = (const float*)d_in[3];
  const float* b1       = (const float*)d_in[4];
  const float* lng      = (const float*)d_in[5];
  const float* lnb      = (const float*)d_in[6];
  const float* W2       = (const float*)d_in[7];
  const float* b2       = (const float*)d_in[8];
  const float* corr     = (const float*)d_in[9];
  const float* dw       = (const float*)d_in[10];
  float* out = (float*)d_out;
  char*  ws  = (char*)d_ws;

  const int BN = (out_size - 1) / (MM * DD + 1);  // B + N
  const int N  = BN - BB;
  const size_t L0 = (size_t)MM * BN * DD;         // start of combined_labels

  int*   counts = (int*)(ws + WS_COUNTS);
  int*   gen    = (int*)(ws + WS_GEN);
  int*   off    = (int*)(ws + WS_OFF);
  float* base   = (float*)(ws + WS_BASE);
  float* proto  = (float*)(ws + WS_PROTO);
  float* mask   = (float*)(ws + WS_MASK);
  float* act    = (float*)(ws + WS_ACT);
  float* big    = (float*)(ws + WS_BIG);          // psum, later gpart

  k_zero<<<32, 256, 0, stream>>>((float*)ws);
  k_count<<<BB / 256, 256, 0, stream>>>(labels, counts, out + L0);
  k_plan<<<1, 128, 0, stream>>>(counts, gen, off, out + L0 + BB, out + L0 + BN,
                                dw, N);
  k_copy_psum<<<dim3(BSPL, DG, MM), 256, 0, stream>>>(features, labels, out,
                                                      big, BN);
  k_proto_final<<<dim3(CC, MM), 256, 0, stream>>>(big, counts, proto, mask);
  k_base<<<dim3(HH / 256, DD / 128, MM), 256, 0, stream>>>(fused, W1, base);
  k_hact<<<dim3(CC, MM), 256, 0, stream>>>(W1, b1, lng, lnb, base, act);
  k_gemm<<<dim3(DG2, KC, MM), 256, 0, stream>>>(act, W2, big);
  k_final<<<dim3(CC, MM), 256, 0, stream>>>(big, proto, mask, b2, corr, gen,
                                            off, out, BN);
}

// Round 2
// 201.868 us; speedup vs baseline: 2.4500x; 2.4500x over previous
//
#include <hip/hip_runtime.h>

namespace {

constexpr int MM = 3;
constexpr int BB = 16384;
constexpr int DD = 1024;
constexpr int CC = 100;
constexpr int HH = 2048;             // 2*DD
constexpr int DESIRED = BB / CC;     // 163
constexpr int RLS = 2048;            // rowlist stride per class (12x headroom)

// class-GEMM geometry
constexpr int KC  = 16, JL = HH / KC;   // 128 j per block
constexpr int DG2 = 4,  DR2 = 256;      // 4 d-groups of 256
constexpr int CH  = CC / 2;             // 50 classes per block (c-split)

// ws byte offsets (gpart region ends at 23.66 MB — known-good footprint)
constexpr size_t WS_COUNTS  = 0;        // 128 int
constexpr size_t WS_GEN     = 512;      // 128 int
constexpr size_t WS_OFF     = 1024;     // 128 int
constexpr size_t WS_BASE    = 2048;     // MM*HH f32 (24 KB)
constexpr size_t WS_MASKSUM = 28672;    // CC*MM*2 f32 (2.4 KB)
constexpr size_t WS_PROTO   = 32768;    // CC*MM*DD f32 (1.2 MB)
constexpr size_t WS_SHARED  = 1310720;  // rowlist int[CC*RLS] (800 KB), later act f32[MM*HH*CC] (2.4 MB)
constexpr size_t WS_GPART   = 4194304;  // MM*DG2*KC*CC*DR2 f32 (19.66 MB)

__global__ void __launch_bounds__(256)
k_zero(float* __restrict__ ws) {
  int i = blockIdx.x * 256 + threadIdx.x;
  if (i < 8192) ws[i] = 0.f;  // counts/gen/off/base (first 32 KB)
}

// count + bin rows by class + emit float labels for combined_labels[:B]
__global__ void __launch_bounds__(256)
k_count(const int* __restrict__ labels, int* __restrict__ counts,
        int* __restrict__ rowlist, float* __restrict__ out_lab) {
  int b = blockIdx.x * 256 + threadIdx.x;
  if (b < BB) {
    int l = labels[b];
    int pos = atomicAdd(&counts[l], 1);
    if (pos < RLS) rowlist[l * RLS + pos] = b;
    out_lab[b] = (float)l;
  }
}

// one block: gen, exclusive offsets, tail labels, loss
__global__ void __launch_bounds__(128)
k_plan(const int* __restrict__ counts, int* __restrict__ gen, int* __restrict__ off,
       float* __restrict__ out_lab_tail, float* __restrict__ out_loss,
       const float* __restrict__ dw, int N) {
  __shared__ int s[128];
  int t = threadIdx.x;
  int cnt = (t < CC) ? counts[t] : 0;
  int g = (t < CC && cnt > 0) ? max(DESIRED - cnt, 0) : 0;
  s[t] = g;
  __syncthreads();
  for (int o = 1; o < 128; o <<= 1) {
    int v = (t >= o) ? s[t - o] : 0;
    __syncthreads();
    s[t] += v;
    __syncthreads();
  }
  int excl = s[t] - g;
  if (t < CC) {
    gen[t] = g;
    off[t] = excl;
    for (int k = 0; k < g; ++k) out_lab_tail[excl + k] = (float)t;
  }
  if (t == 0) *out_loss = (N > 0) ? 0.1f * dw[0] : 0.0f;
}

// Fused: per-class gather -> register accumulate (no atomics) + features copy.
// block (c, m, dh): 256 threads x float2 covers 512 contiguous floats.
__global__ void __launch_bounds__(256)
k_gather(const float* __restrict__ feat, const int* __restrict__ rowlist,
         const int* __restrict__ counts, float* __restrict__ out,
         float* __restrict__ proto, float* __restrict__ masksum, int BN) {
  int c = blockIdx.x, m = blockIdx.y, dh = blockIdx.z, t = threadIdx.x;
  int d0 = dh * 512 + t * 2;
  int cnt = min(counts[c], RLS);
  const int* rl = rowlist + c * RLS;
  const float* fb = feat + (size_t)m * BB * DD + d0;
  float* ob = out + (size_t)m * BN * DD + d0;
  float ax = 0.f, ay = 0.f;
  int i = 0;
  for (; i + 4 <= cnt; i += 4) {
    int r0 = rl[i], r1 = rl[i + 1], r2 = rl[i + 2], r3 = rl[i + 3];
    const float2 v0 = *reinterpret_cast<const float2*>(fb + (size_t)r0 * DD);
    const float2 v1 = *reinterpret_cast<const float2*>(fb + (size_t)r1 * DD);
    const float2 v2 = *reinterpret_cast<const float2*>(fb + (size_t)r2 * DD);
    const float2 v3 = *reinterpret_cast<const float2*>(fb + (size_t)r3 * DD);
    *reinterpret_cast<float2*>(ob + (size_t)r0 * DD) = v0;
    *reinterpret_cast<float2*>(ob + (size_t)r1 * DD) = v1;
    *reinterpret_cast<float2*>(ob + (size_t)r2 * DD) = v2;
    *reinterpret_cast<float2*>(ob + (size_t)r3 * DD) = v3;
    ax += v0.x + v1.x + v2.x + v3.x;
    ay += v0.y + v1.y + v2.y + v3.y;
  }
  for (; i < cnt; ++i) {
    int r = rl[i];
    const float2 v = *reinterpret_cast<const float2*>(fb + (size_t)r * DD);
    *reinterpret_cast<float2*>(ob + (size_t)r * DD) = v;
    ax += v.x; ay += v.y;
  }
  float inv = cnt > 0 ? 1.f / (float)cnt : 0.f;
  float px = ax * inv, py = ay * inv;
  float2 pv; pv.x = px; pv.y = py;
  *reinterpret_cast<float2*>(proto + ((size_t)c * MM + m) * DD + d0) = pv;
  __shared__ float red[256];
  red[t] = px + py;
  __syncthreads();
  for (int o = 128; o > 0; o >>= 1) {
    if (t < o) red[t] += red[t + o];
    __syncthreads();
  }
  if (t == 0) masksum[(c * MM + m) * 2 + dh] = red[0];
}

// base[m][j] = sum_d fused0[d] * W1[m][d][j]
__global__ void __launch_bounds__(256)
k_base(const float* __restrict__ fused, const float* __restrict__ W1,
       float* __restrict__ base) {
  int jb = blockIdx.x, db = blockIdx.y, m = blockIdx.z, t = threadIdx.x;
  int j = jb * 256 + t;
  const float* w = W1 + ((size_t)m * (DD + CC)) * HH + j;
  float acc = 0.f;
  int dlo = db * 64;
  for (int d = dlo; d < dlo + 64; ++d)
    acc = fmaf(fused[d], w[(size_t)d * HH], acc);
  atomicAdd(&base[m * HH + j], acc);
}

// h = base + W1[m][D+c] + b1 -> layernorm -> leaky -> act[m][j][c]
__global__ void __launch_bounds__(256)
k_hact(const float* __restrict__ W1, const float* __restrict__ b1,
       const float* __restrict__ lng, const float* __restrict__ lnb,
       const float* __restrict__ base, float* __restrict__ act) {
  int c = blockIdx.x, m = blockIdx.y, t = threadIdx.x;
  const float* w1row = W1 + ((size_t)m * (DD + CC) + DD + c) * HH;
  float h[8];
  float s = 0.f, s2 = 0.f;
#pragma unroll
  for (int k = 0; k < 8; ++k) {
    int j = t + k * 256;
    float v = base[m * HH + j] + w1row[j] + b1[m * HH + j];
    h[k] = v; s += v; s2 += v * v;
  }
  __shared__ float rs[256], rs2[256];
  rs[t] = s; rs2[t] = s2;
  __syncthreads();
  for (int o = 128; o > 0; o >>= 1) {
    if (t < o) { rs[t] += rs[t + o]; rs2[t] += rs2[t + o]; }
    __syncthreads();
  }
  float mu = rs[0] * (1.f / HH);
  float var = rs2[0] * (1.f / HH) - mu * mu;
  float rstd = rsqrtf(var + 1e-5f);
  float* ao = act + (size_t)m * HH * CC;
#pragma unroll
  for (int k = 0; k < 8; ++k) {
    int j = t + k * 256;
    float v = (h[k] - mu) * rstd * lng[m * HH + j] + lnb[m * HH + j];
    v = v > 0.f ? v : 0.2f * v;
    ao[(size_t)j * CC + c] = v;
  }
}

// gpart[m][dg][kc][c][d'] = sum_{j in chunk} act[m][j][c] * W2[m][j][d]
// c-split (2x50) -> 384 blocks, acc[50] keeps VGPR moderate.
__global__ void __launch_bounds__(256)
k_gemm(const float* __restrict__ act, const float* __restrict__ W2,
       float* __restrict__ gpart) {
  int dg = blockIdx.x, kc = blockIdx.y;
  int m = blockIdx.z >> 1, ch = blockIdx.z & 1;
  int t = threadIdx.x;
  int d = dg * DR2 + t;
  int j0 = kc * JL, c0 = ch * CH;
  float acc[CH];
#pragma unroll
  for (int c = 0; c < CH; ++c) acc[c] = 0.f;
  const float* ab = act + ((size_t)m * HH + j0) * CC + c0;
  const float* wb = W2 + ((size_t)m * HH + j0) * DD + d;
  for (int j = 0; j < JL; ++j) {
    float w2v = wb[(size_t)j * DD];
    const float* aj = ab + (size_t)j * CC;   // uniform -> s_loads
#pragma unroll
    for (int c = 0; c < CH; ++c) acc[c] = fmaf(aj[c], w2v, acc[c]);
  }
  float* pb = gpart + ((size_t)(m * DG2 + dg) * KC + kc) * (CC * DR2)
            + (size_t)c0 * DR2 + t;
#pragma unroll
  for (int c = 0; c < CH; ++c) pb[(size_t)c * DR2] = acc[c];
}

// g = sum_kc gpart + b2 -> blend with protos -> scatter to rows of class c
__global__ void __launch_bounds__(256)
k_final(const float* __restrict__ gpart, const float* __restrict__ proto,
        const float* __restrict__ masksum, const float* __restrict__ b2,
        const float* __restrict__ corr, const int* __restrict__ gen,
        const int* __restrict__ off, float* __restrict__ out, int BN) {
  int c = blockIdx.x, m = blockIdx.y, t = threadIdx.x;
  int g = gen[c];
  if (g == 0) return;
  int d0 = t * 4, dg = d0 >> 8, dsub = d0 & 255;
  float4 a = {0.f, 0.f, 0.f, 0.f};
#pragma unroll
  for (int kc = 0; kc < KC; ++kc) {
    const float4 v = *reinterpret_cast<const float4*>(
        &gpart[((size_t)(m * DG2 + dg) * KC + kc) * (CC * DR2) + c * DR2 + dsub]);
    a.x += v.x; a.y += v.y; a.z += v.z; a.w += v.w;
  }
  const float4 bb = *reinterpret_cast<const float4*>(&b2[m * DD + d0]);
  a.x += bb.x; a.y += bb.y; a.z += bb.z; a.w += bb.w;
#pragma unroll
  for (int om = 0; om < MM; ++om) {
    if (om == m) continue;
    float msum = masksum[(c * MM + om) * 2] + masksum[(c * MM + om) * 2 + 1];
    float al = corr[m * MM + om] * (msum > 0.f ? 1.f : 0.f);
    float ia = 1.f - al;
    const float4 p = *reinterpret_cast<const float4*>(
        &proto[((size_t)c * MM + om) * DD + d0]);
    a.x = a.x * ia + p.x * al;
    a.y = a.y * ia + p.y * al;
    a.z = a.z * ia + p.z * al;
    a.w = a.w * ia + p.w * al;
  }
  int row0 = BB + off[c];
  for (int k = 0; k < g; ++k)
    *reinterpret_cast<float4*>(&out[((size_t)m * BN + row0 + k) * DD + d0]) = a;
}

}  // namespace

extern "C" void kernel_launch(void* const* d_in, const int* in_sizes, int n_in,
                              void* d_out, int out_size, void* d_ws, size_t ws_size,
                              hipStream_t stream) {
  const float* features = (const float*)d_in[0];
  const float* fused    = (const float*)d_in[1];
  const int*   labels   = (const int*)d_in[2];
  const float* W1       = (const float*)d_in[3];
  const float* b1       = (const float*)d_in[4];
  const float* lng      = (const float*)d_in[5];
  const float* lnb      = (const float*)d_in[6];
  const float* W2       = (const float*)d_in[7];
  const float* b2       = (const float*)d_in[8];
  const float* corr     = (const float*)d_in[9];
  const float* dw       = (const float*)d_in[10];
  float* out = (float*)d_out;
  char*  ws  = (char*)d_ws;

  const int BN = (out_size - 1) / (MM * DD + 1);  // B + N
  const int N  = BN - BB;
  const size_t L0 = (size_t)MM * BN * DD;         // start of combined_labels

  int*   counts  = (int*)(ws + WS_COUNTS);
  int*   gen     = (int*)(ws + WS_GEN);
  int*   off     = (int*)(ws + WS_OFF);
  float* base    = (float*)(ws + WS_BASE);
  float* masksum = (float*)(ws + WS_MASKSUM);
  float* proto   = (float*)(ws + WS_PROTO);
  int*   rowlist = (int*)(ws + WS_SHARED);        // dead after k_gather
  float* act     = (float*)(ws + WS_SHARED);      // live k_hact..k_gemm
  float* gpart   = (float*)(ws + WS_GPART);

  k_zero<<<32, 256, 0, stream>>>((float*)ws);
  k_count<<<BB / 256, 256, 0, stream>>>(labels, counts, rowlist, out + L0);
  k_plan<<<1, 128, 0, stream>>>(counts, gen, off, out + L0 + BB, out + L0 + BN,
                                dw, N);
  k_gather<<<dim3(CC, MM, 2), 256, 0, stream>>>(features, rowlist, counts, out,
                                                proto, masksum, BN);
  k_base<<<dim3(HH / 256, DD / 64, MM), 256, 0, stream>>>(fused, W1, base);
  k_hact<<<dim3(CC, MM), 256, 0, stream>>>(W1, b1, lng, lnb, base, act);
  k_gemm<<<dim3(DG2, KC, MM * 2), 256, 0, stream>>>(act, W2, gpart);
  k_final<<<dim3(CC, MM), 256, 0, stream>>>(gpart, proto, masksum, b2, corr,
                                            gen, off, out, BN);
}